// Round 9
// baseline (100.294 us; speedup 1.0000x reference)
//
#include <hip/hip_runtime.h>
#include <stdint.h>

// Problem constants
#define S_LEN 2048
#define D_DIM 1024
#define NB 2
#define NH 16
#define NE 64
#define M_ROWS (NB * S_LEN)   // 4096
#define N_COLS (3 * NH * NE)  // 3072 (Q | K | V column blocks)
#define K_DIM D_DIM           // 1024

typedef unsigned short u16;
typedef unsigned int u32;
typedef u16 u16x8 __attribute__((ext_vector_type(8)));
typedef __bf16 bf16x8 __attribute__((ext_vector_type(8)));
typedef float f32x4 __attribute__((ext_vector_type(4)));

__device__ __forceinline__ u16 f2b(float f) {
  u32 u = __builtin_bit_cast(u32, f);
  return (u16)((u + 0x7FFFu + ((u >> 16) & 1u)) >> 16);  // RNE
}

__device__ __forceinline__ void gload_lds16(const void* g, void* l) {
  __builtin_amdgcn_global_load_lds(
      (const __attribute__((address_space(1))) u32*)g,
      (__attribute__((address_space(3))) u32*)l, 16, 0, 0);
}

// ---------- merged prep: blocks [0,2048) convert x; [2048,2816) transpose W ----------
__global__ __launch_bounds__(256) void k_prep(const float* __restrict__ x,
                                              const float* __restrict__ Wq,
                                              const float* __restrict__ Wk,
                                              const float* __restrict__ Wv,
                                              u16* __restrict__ xb,
                                              u16* __restrict__ Wt) {
  __shared__ u16 tile[64][65];
  int bid = blockIdx.x;
  int t = threadIdx.x;
  if (bid < 2048) {
    // x: f32 -> bf16, 8 elems/thread, vectorized
    size_t i = (size_t)bid * 256 + t;
    const float4* xf = (const float4*)x;
    float4 a = xf[2 * i], c = xf[2 * i + 1];
    u16x8 o;
    o[0] = f2b(a.x); o[1] = f2b(a.y); o[2] = f2b(a.z); o[3] = f2b(a.w);
    o[4] = f2b(c.x); o[5] = f2b(c.y); o[6] = f2b(c.z); o[7] = f2b(c.w);
    *(u16x8*)(xb + 8 * i) = o;
  } else {
    // W[H][D][E] f32 (x3) -> Wt[3*H*E][D] bf16 (B^T layout)
    int wbid = bid - 2048;             // proj*256 + h*16 + kb
    int kb = wbid & 15;
    int h = (wbid >> 4) & 15;
    int proj = wbid >> 8;
    const float* W = (proj == 0) ? Wq : ((proj == 1) ? Wk : Wv);
    int k0 = kb * 64;
    int e = t & 63, kr = t >> 6;
    const float* src = W + ((size_t)h * D_DIM + k0 + kr * 16) * NE + e;
#pragma unroll
    for (int j = 0; j < 16; ++j) tile[kr * 16 + j][e] = f2b(src[(size_t)j * NE]);
    __syncthreads();
    int e2 = t >> 2, kc = (t & 3) * 16;
    u16x8 o0, o1;
#pragma unroll
    for (int j = 0; j < 8; ++j) { o0[j] = tile[kc + j][e2]; o1[j] = tile[kc + 8 + j][e2]; }
    size_t n = (size_t)proj * 1024 + h * 64 + e2;
    u16* dst = Wt + n * K_DIM + k0 + kc;
    *(u16x8*)dst = o0;
    *(u16x8*)(dst + 8) = o1;
  }
}

// ------------- GEMM: qkv[4096,3072] = xb[4096,1024] @ Wt[3072,1024]^T -------------
// 1D grid 768, XCD-aware decode: xcd = bid&7 owns n-panels {3*xcd..3*xcd+2}
// (768 KB of B resident per XCD L2); A-panel reused by 3 consecutive same-XCD
// blocks. Q columns (col<1024) pre-scaled by 0.125*log2(e) for exp2-domain attn.
__global__ __launch_bounds__(256) void k_gemm(const u16* __restrict__ A,
                                              const u16* __restrict__ Bt,
                                              u16* __restrict__ C) {
  __shared__ __align__(16) u16 As[128 * 64];
  __shared__ __align__(16) u16 Bs[128 * 64];
  int t = threadIdx.x;
  int lane = t & 63, w = t >> 6;
  int wr = (w >> 1) * 64, wc = (w & 1) * 64;
  int bid = blockIdx.x;
  int xcd = bid & 7, r0 = bid >> 3;          // r0 in [0,96)
  int m0 = (r0 / 3) * 128;
  int n0 = (xcd * 3 + (r0 % 3)) * 128;
  float qscale = ((n0 + wc) < 1024) ? 0.18033688f : 1.0f;  // 0.125*log2e
  f32x4 acc[4][4];
#pragma unroll
  for (int m = 0; m < 4; m++)
#pragma unroll
    for (int n = 0; n < 4; n++)
#pragma unroll
      for (int j = 0; j < 4; j++) acc[m][n][j] = 0.f;

  for (int k0 = 0; k0 < K_DIM; k0 += 64) {
#pragma unroll
    for (int i = 0; i < 4; ++i) {
      int ci = i * 256 + t;
      int row = ci >> 3, c = ci & 7;
      int cs = c ^ (row & 7);
      gload_lds16(A + (size_t)(m0 + row) * K_DIM + k0 + cs * 8,
                  (char*)As + (size_t)(i * 256 + w * 64) * 16);
      gload_lds16(Bt + (size_t)(n0 + row) * K_DIM + k0 + cs * 8,
                  (char*)Bs + (size_t)(i * 256 + w * 64) * 16);
    }
    __syncthreads();
#pragma unroll
    for (int ks = 0; ks < 2; ++ks) {
      int kc = ks * 4 + (lane >> 4);
      bf16x8 af[4], bfr[4];
#pragma unroll
      for (int m = 0; m < 4; m++) {
        int r = wr + m * 16 + (lane & 15);
        af[m] = *(const bf16x8*)&As[r * 64 + ((kc ^ (r & 7)) * 8)];
      }
#pragma unroll
      for (int n = 0; n < 4; n++) {
        int r = wc + n * 16 + (lane & 15);
        bfr[n] = *(const bf16x8*)&Bs[r * 64 + ((kc ^ (r & 7)) * 8)];
      }
#pragma unroll
      for (int m = 0; m < 4; m++)
#pragma unroll
        for (int n = 0; n < 4; n++)
          acc[m][n] = __builtin_amdgcn_mfma_f32_16x16x32_bf16(af[m], bfr[n], acc[m][n], 0, 0, 0);
    }
    __syncthreads();
  }
#pragma unroll
  for (int m = 0; m < 4; m++) {
#pragma unroll
    for (int r = 0; r < 4; r++) {
      int row = m0 + wr + m * 16 + (lane >> 4) * 4 + r;
#pragma unroll
      for (int n = 0; n < 4; n++) {
        int col = n0 + wc + n * 16 + (lane & 15);
        C[(size_t)row * N_COLS + col] = f2b(acc[m][n][r] * qscale);
      }
    }
  }
}

// ---- attention helpers (512-thread block) ----
__device__ __forceinline__ void stage_k(const u16* kb_, u16* kdst, int kv0, int t) {
  int row = t >> 3, c = t & 7;           // 512 threads cover 64 rows x 8 chunks
  int cs = c ^ (row & 7);
  gload_lds16(kb_ + (size_t)(kv0 + row) * N_COLS + cs * 8,
              (char*)kdst + (size_t)t * 16);
}

// V write: thread (t<256) covers kv pair vp = t>>3, e-chunk vec = t&7.
// Vt element (e,kv) at byte e*128 + slot*16 + (kv&7)*2, slot=(kv>>3)^(e&7)^(e>>3).
__device__ __forceinline__ void vwrite(u16* vt, u16x8 va, u16x8 vb2, int vp, int vec) {
#pragma unroll
  for (int j = 0; j < 8; ++j) {
    int e = vec * 8 + j;
    int slot = (vp >> 2) ^ (e & 7) ^ (e >> 3);
    *(u32*)((char*)vt + e * 128 + slot * 16 + (vp & 3) * 4) =
        (u32)va[j] | ((u32)vb2[j] << 16);
  }
}

// ------------- flash attention, causal, QBLK=128, 8 waves, no-max softmax -------------
// 512 blocks (2/CU, 16 waves/CU). One K/V staging + barrier pair serves 128 q-rows
// (2x amortization vs QBLK=64). Decode: xcd=bid&7, g=bid>>3; bh = xcd*4+(g&3)
// (4 heads' K/V = 2 MB per XCD L2); qb = 15-(g>>2) (LPT: longest first).
// nt = 2qb+2 kv-tiles; last TWO tiles masked per-element (lower q-half's final
// tile fully masked - correct by construction). No-max softmax: s = 0.18*q.k
// bounded ~|9| -> p = exp2(s) directly; l per-lane, one shuffle-reduce at end.
__global__ __launch_bounds__(512) void k_attn(const u16* __restrict__ qkv,
                                              float* __restrict__ out) {
  __shared__ __align__(16) u16 Ks[2][64 * 64];
  __shared__ __align__(16) u16 Vt[2][64 * 64];
  __shared__ __align__(16) u16 Ps[128 * 64];
  int t = threadIdx.x;
  int lane = t & 63, w = t >> 6;        // w in [0,8)
  int bid = blockIdx.x;                 // 0..511
  int xcd = bid & 7, g = bid >> 3;
  int bh = xcd * 4 + (g & 3);
  int qb = 15 - (g >> 2);
  int b = bh >> 4, h = bh & 15;
  const u16* qb_ = qkv + (size_t)b * S_LEN * N_COLS + h * NE;
  const u16* kb_ = qb_ + 1024;
  const u16* vb_ = qb_ + 2048;
  int vp = t >> 3, vec = t & 7;         // V staging (threads < 256)

  int q0 = qb * 128;
  int nt = 2 * qb + 2;

  int qrow = q0 + w * 16 + (lane & 15);
  bf16x8 qf[2];
#pragma unroll
  for (int ks = 0; ks < 2; ks++)
    qf[ks] = *(const bf16x8*)(qb_ + (size_t)qrow * N_COLS + ks * 32 + (lane >> 4) * 8);

  f32x4 o[4];
#pragma unroll
  for (int i = 0; i < 4; i++)
#pragma unroll
    for (int j = 0; j < 4; j++) o[i][j] = 0.f;
  float lrow[4];
#pragma unroll
  for (int r = 0; r < 4; r++) lrow[r] = 0.f;
  int myq = q0 + w * 16 + (lane >> 4) * 4;  // + r

  // prologue: stage tile 0 into buffer 0
  stage_k(kb_, Ks[0], 0, t);
  if (t < 256) {
    const u16* vs = vb_ + (size_t)(2 * vp) * N_COLS + vec * 8;
    u16x8 va = *(const u16x8*)vs;
    u16x8 vb2 = *(const u16x8*)(vs + N_COLS);
    vwrite(Vt[0], va, vb2, vp, vec);
  }
  __syncthreads();

  int cur = 0;
  for (int ti = 0; ti < nt; ++ti) {
    int kv0 = ti * 64;
    bool pf = (ti + 1 < nt);
    u16x8 va, vb2;
    if (pf) {
      if (t < 256) {
        const u16* vs = vb_ + (size_t)(kv0 + 64 + 2 * vp) * N_COLS + vec * 8;
        va = *(const u16x8*)vs;          // in flight during QK^T+softmax
        vb2 = *(const u16x8*)(vs + N_COLS);
      }
      stage_k(kb_, Ks[cur ^ 1], kv0 + 64, t);
    }

    // S = Q K^T
    f32x4 s[4];
#pragma unroll
    for (int f = 0; f < 4; f++)
#pragma unroll
      for (int j = 0; j < 4; j++) s[f][j] = 0.f;
    __builtin_amdgcn_s_setprio(1);
#pragma unroll
    for (int ks = 0; ks < 2; ks++) {
      int kc = ks * 4 + (lane >> 4);
#pragma unroll
      for (int f = 0; f < 4; f++) {
        int r = f * 16 + (lane & 15);
        bf16x8 kf = *(const bf16x8*)&Ks[cur][r * 64 + ((kc ^ (r & 7)) * 8)];
        s[f] = __builtin_amdgcn_mfma_f32_16x16x32_bf16(qf[ks], kf, s[f], 0, 0, 0);
      }
    }
    __builtin_amdgcn_s_setprio(0);

    // no-max softmax: p = exp2(s); mask last two tiles per-element.
    bool mask = (ti >= nt - 2);
#pragma unroll
    for (int r = 0; r < 4; ++r) {
#pragma unroll
      for (int f = 0; f < 4; f++) {
        float p = __builtin_amdgcn_exp2f(s[f][r]);
        if (mask) {
          int kv = kv0 + f * 16 + (lane & 15);
          p = (kv <= myq + r) ? p : 0.f;
        }
        s[f][r] = p;
      }
      lrow[r] += (s[0][r] + s[1][r]) + (s[2][r] + s[3][r]);
    }

    // P -> LDS bf16 (own-wave rows; read by same wave only)
#pragma unroll
    for (int f = 0; f < 4; f++) {
#pragma unroll
      for (int r = 0; r < 4; r++) {
        int row = w * 16 + (lane >> 4) * 4 + r;
        int col = f * 16 + (lane & 15);
        int swz = (col >> 3) ^ (row & 7);
        *(u16*)((char*)Ps + row * 128 + swz * 16 + (col & 7) * 2) =
            __builtin_bit_cast(u16, (__bf16)s[f][r]);
      }
    }

    // T14 write-late: V prefetch regs -> next buffer
    if (pf && t < 256) vwrite(Vt[cur ^ 1], va, vb2, vp, vec);

    // PV  (Ps rows are 64 u16 = 128 B; row index pr -> u16 offset pr*64)
    __builtin_amdgcn_s_setprio(1);
#pragma unroll
    for (int ks = 0; ks < 2; ks++) {
      int kc = ks * 4 + (lane >> 4);
      int pr = w * 16 + (lane & 15);
      bf16x8 pa = *(const bf16x8*)&Ps[pr * 64 + ((kc ^ (pr & 7)) * 8)];
#pragma unroll
      for (int ef = 0; ef < 4; ef++) {
        int vr = ef * 16 + (lane & 15);
        int vswz = kc ^ (vr & 7) ^ (vr >> 3);
        bf16x8 vbf = *(const bf16x8*)&Vt[cur][vr * 64 + vswz * 8];
        o[ef] = __builtin_amdgcn_mfma_f32_16x16x32_bf16(pa, vbf, o[ef], 0, 0, 0);
      }
    }
    __builtin_amdgcn_s_setprio(0);
    __syncthreads();
    cur ^= 1;
  }

  // epilogue: reduce l across the 16-lane col groups once, then normalize
#pragma unroll
  for (int r = 0; r < 4; r++) {
    float l = lrow[r];
    l += __shfl_xor(l, 1);
    l += __shfl_xor(l, 2);
    l += __shfl_xor(l, 4);
    l += __shfl_xor(l, 8);
    float inv = 1.0f / l;
    int q = myq + r;
#pragma unroll
    for (int ef = 0; ef < 4; ef++) {
      int col = h * NE + ef * 16 + (lane & 15);
      out[((size_t)b * S_LEN + q) * (NH * NE) + col] = o[ef][r] * inv;
    }
  }
}

extern "C" void kernel_launch(void* const* d_in, const int* in_sizes, int n_in,
                              void* d_out, int out_size, void* d_ws, size_t ws_size,
                              hipStream_t stream) {
  const float* x = (const float*)d_in[0];
  const float* Wq = (const float*)d_in[1];
  const float* Wk = (const float*)d_in[2];
  const float* Wv = (const float*)d_in[3];
  float* out = (float*)d_out;

  char* ws = (char*)d_ws;
  u16* xb = (u16*)ws;                          // 4096*1024*2  = 8 MB
  u16* Wt = (u16*)(ws + (8u << 20));           // 3072*1024*2  = 6 MB
  u16* qkv = (u16*)(ws + (14u << 20));         // 4096*3072*2  = 24 MB

  k_prep<<<dim3(2816), dim3(256), 0, stream>>>(x, Wq, Wk, Wv, xb, Wt);
  k_gemm<<<dim3(768), dim3(256), 0, stream>>>(xb, Wt, qkv);
  k_attn<<<dim3(512), dim3(512), 0, stream>>>(qkv, out);
}